// Round 4
// baseline (38.452 us; speedup 1.0000x reference)
//
#include <hip/hip_runtime.h>

// Problem constants (B=4, N=2048 fixed by the reference setup)
#define BB 4
#define NN 2048
#define TS 256                                  // n-tile rows per block
#define TT (NN / TS)                            // 8 tiles per batch
#define NPAIRS (TT * (TT + 1) / 2)              // 36 unordered tile pairs (incl. diag)
#define MC 32                                   // m-points staged per job
#define MSPL (TS / MC)                          // 8 m-chunks per tile pair
#define JOBS_PER_B (NPAIRS * MSPL)              // 288
#define NJOBS (JOBS_PER_B * BB)                 // 1152 blocks
#define BLK 256                                 // 4 waves
#define ROWS 4                                  // n-rows per thread (wave covers all 256)
#define MPW (MC / 4)                            // 8 m-points per wave
// every surviving (m<n) pair carries weight 2 -> fold into final scale
#define SCALE (2.0f / ((float)BB * (float)NN * (float)NN))

__device__ __forceinline__ void quat_to_R(float qw, float qx, float qy, float qz, float* R) {
    R[0] = 1.f - 2.f * (qy * qy + qz * qz);
    R[1] = 2.f * (qx * qy - qz * qw);
    R[2] = 2.f * (qx * qz + qy * qw);
    R[3] = 2.f * (qx * qy + qz * qw);
    R[4] = 1.f - 2.f * (qx * qx + qz * qz);
    R[5] = 2.f * (qy * qz - qx * qw);
    R[6] = 2.f * (qx * qz - qy * qw);
    R[7] = 2.f * (qy * qz + qx * qw);
    R[8] = 1.f - 2.f * (qx * qx + qy * qy);
}

// Lower-triangle (m<n) pair sum, weight 2 in SCALE.
// Block = (batch, tile-pair, m-chunk). Each thread owns 4 n-rows
// {lane, lane+64, lane+128, lane+192} of the n-tile; the 4 waves split the
// 32 staged m-points (8 each) -> 5 LDS b128 broadcasts amortized over 256 pairs.
template <bool ATOMIC>
__global__ __launch_bounds__(BLK, 4) void pair_kernel(
    const float* __restrict__ xyz, const float* __restrict__ scales,
    const float* __restrict__ rot, const float* __restrict__ vel,
    float* __restrict__ partials, unsigned int* __restrict__ counter,
    float* __restrict__ outp)
{
    __shared__ float4 sm[MC][5];
    __shared__ float wsum[BLK / 64];
    __shared__ int lastflag;

    const int tid  = threadIdx.x;
    const int lane = tid & 63;
    const int w    = tid >> 6;
    const int jid  = blockIdx.x;
    const int b    = jid / JOBS_PER_B;
    const int rem  = jid % JOBS_PER_B;
    const int p    = rem / MSPL;    // triangular tile-pair index
    const int mc   = rem % MSPL;    // m-chunk

    // decode p -> (ti >= tj)
    int ti = 0;
    while ((ti + 1) * (ti + 2) / 2 <= p) ++ti;
    const int tj = p - ti * (ti + 1) / 2;
    const bool diag = (ti == tj);

    const int n_base = ti * TS;
    const int m_blk  = tj * TS + mc * MC;

    // ---- stage m-chunk into LDS (threads 0..31, one point each) ----
    if (tid < MC) {
        const int m = m_blk + tid;
        const size_t i3 = ((size_t)b * NN + m) * 3;
        const size_t i4 = ((size_t)b * NN + m) * 4;
        const float4 q = *reinterpret_cast<const float4*>(rot + i4);
        float R[9];
        quat_to_R(q.x, q.y, q.z, q.w, R);
        sm[tid][0] = make_float4(xyz[i3], xyz[i3 + 1], xyz[i3 + 2], scales[i3]);
        sm[tid][1] = make_float4(scales[i3 + 1], scales[i3 + 2], vel[i3], vel[i3 + 1]);
        sm[tid][2] = make_float4(vel[i3 + 2], R[0], R[1], R[2]);
        sm[tid][3] = make_float4(R[3], R[4], R[5], R[6]);
        sm[tid][4] = make_float4(R[7], R[8], 0.f, 0.f);
    }

    // ---- own n-rows in registers (4 per thread) ----
    float px[ROWS], py[ROWS], pz[ROWS];
    float sx[ROWS], sy[ROWS], sz[ROWS];
    float vx[ROWS], vy[ROWS], vz[ROWS];
    float Rn[ROWS][9];
    int   nidx[ROWS];
    #pragma unroll
    for (int r = 0; r < ROWS; ++r) {
        const int n = n_base + lane + 64 * r;
        nidx[r] = n;
        const size_t i3 = ((size_t)b * NN + n) * 3;
        const size_t i4 = ((size_t)b * NN + n) * 4;
        px[r] = xyz[i3]; py[r] = xyz[i3 + 1]; pz[r] = xyz[i3 + 2];
        sx[r] = scales[i3]; sy[r] = scales[i3 + 1]; sz[r] = scales[i3 + 2];
        vx[r] = vel[i3]; vy[r] = vel[i3 + 1]; vz[r] = vel[i3 + 2];
        const float4 q = *reinterpret_cast<const float4*>(rot + i4);
        quat_to_R(q.x, q.y, q.z, q.w, Rn[r]);
    }

    __syncthreads();

    float acc = 0.f;
    const int jb = w * MPW;   // this wave's m-subrange (uniform in wave)

    auto inner = [&](bool isDiag) {
        #pragma unroll 2
        for (int jj = 0; jj < MPW; ++jj) {
            const int j = jb + jj;
            const int m = m_blk + j;
            const float4 c0 = sm[j][0];
            const float4 c1 = sm[j][1];
            const float4 c2 = sm[j][2];
            const float4 c3 = sm[j][3];
            const float4 c4 = sm[j][4];
            #pragma unroll
            for (int r = 0; r < ROWS; ++r) {
                const float dx = px[r] - c0.x, dy = py[r] - c0.y, dz = pz[r] - c0.z;
                const float d2 = fmaf(dx, dx, fmaf(dy, dy, fmaf(dz, dz, 1e-8f)));
                const float rinv = __builtin_amdgcn_rsqf(d2);
                // r_dir(n,m): (diff^T R_n) scaled by s_m
                const float a0 = fmaf(dx, Rn[r][0], fmaf(dy, Rn[r][3], dz * Rn[r][6])) * c0.w;
                const float a1 = fmaf(dx, Rn[r][1], fmaf(dy, Rn[r][4], dz * Rn[r][7])) * c1.x;
                const float a2 = fmaf(dx, Rn[r][2], fmaf(dy, Rn[r][5], dz * Rn[r][8])) * c1.y;
                const float qa = __builtin_amdgcn_sqrtf(fmaf(a0, a0, fmaf(a1, a1, a2 * a2)));
                // r_dir(m,n): (diff^T R_m) scaled by s_n (sign dies in the square)
                const float b0 = fmaf(dx, c2.y, fmaf(dy, c3.x, dz * c3.w)) * sx[r];
                const float b1 = fmaf(dx, c2.z, fmaf(dy, c3.y, dz * c4.x)) * sy[r];
                const float b2 = fmaf(dx, c2.w, fmaf(dy, c3.z, dz * c4.y)) * sz[r];
                const float qb = __builtin_amdgcn_sqrtf(fmaf(b0, b0, fmaf(b1, b1, b2 * b2)));
                // overlap = rinv * relu(qa + qb - d2)
                const float ww = fmaxf(qa + qb - d2, 0.f);
                const float ov = ww * rinv;
                const float rc = __builtin_amdgcn_rcpf(fmaf(0.1f, ov, 1.f));
                // v_approach = (v_n - v_m).diff * rinv ; ramp = relu(-v_approach)
                const float vdot = fmaf(vx[r] - c1.z, dx,
                                   fmaf(vy[r] - c1.w, dy, (vz[r] - c2.x) * dz));
                const float ramp = fmaxf(-vdot * rinv, 0.f);
                // t = spec + 0.1*ov*ramp = ov * (ov*rc + 0.1*ramp)
                float t = ov * fmaf(ov, rc, 0.1f * ramp);
                if (isDiag && !(m < nidx[r])) t = 0.f;   // diag tiles: keep m<n only
                acc += t;
            }
        }
    };
    if (diag) inner(true); else inner(false);

    // ---- block reduction (4 waves) ----
    #pragma unroll
    for (int off = 32; off > 0; off >>= 1)
        acc += __shfl_down(acc, off, 64);
    if (lane == 0) wsum[w] = acc;
    __syncthreads();

    if (ATOMIC) {
        if (tid == 0) atomicAdd(outp, (wsum[0] + wsum[1] + wsum[2] + wsum[3]) * SCALE);
        return;
    }

    if (tid == 0) {
        const float tot = wsum[0] + wsum[1] + wsum[2] + wsum[3];
        partials[jid] = tot;
        __threadfence();                               // release
        const unsigned int done = atomicAdd(counter, 1u);
        lastflag = (done == (unsigned int)(NJOBS - 1));
    }
    __syncthreads();

    if (lastflag && tid < 64) {
        __threadfence();                               // acquire
        const float4* p4 = reinterpret_cast<const float4*>(partials);
        float s = 0.f;
        for (int i = tid; i < NJOBS / 4; i += 64) {
            const float4 v = p4[i];
            s += v.x + v.y + v.z + v.w;
        }
        #pragma unroll
        for (int off = 32; off > 0; off >>= 1)
            s += __shfl_down(s, off, 64);
        if (tid == 0) outp[0] = s * SCALE;
    }
}

extern "C" void kernel_launch(void* const* d_in, const int* in_sizes, int n_in,
                              void* d_out, int out_size, void* d_ws, size_t ws_size,
                              hipStream_t stream)
{
    const float* xyz    = (const float*)d_in[0];
    const float* scales = (const float*)d_in[1];
    const float* rot    = (const float*)d_in[2];
    const float* vel    = (const float*)d_in[3];
    float* out = (float*)d_out;

    if (ws_size >= 256 + NJOBS * sizeof(float)) {
        unsigned int* counter = (unsigned int*)d_ws;
        float* partials = (float*)((char*)d_ws + 256);
        hipMemsetAsync(counter, 0, sizeof(unsigned int), stream);   // graph-safe
        pair_kernel<false><<<NJOBS, BLK, 0, stream>>>(xyz, scales, rot, vel,
                                                      partials, counter, out);
    } else {
        hipMemsetAsync(d_out, 0, sizeof(float), stream);
        pair_kernel<true><<<NJOBS, BLK, 0, stream>>>(xyz, scales, rot, vel,
                                                     nullptr, nullptr, out);
    }
}